// Round 6
// baseline (287.006 us; speedup 1.0000x reference)
//
#include <hip/hip_runtime.h>

#define AS1 __attribute__((address_space(1)))
#define AS3 __attribute__((address_space(3)))

using bf16x8  = __attribute__((ext_vector_type(8))) __bf16;
using floatx4 = __attribute__((ext_vector_type(4))) float;
using short4v = __attribute__((ext_vector_type(4))) short;

#define SCQ 0.18033688f   // (1/sqrt(64)) * log2(e), folded into Q weights/bias

#if __has_builtin(__builtin_amdgcn_mfma_f32_16x16x16bf16_1k)
#define HAVE_MFMA16 1
#else
#define HAVE_MFMA16 0
#endif

__device__ inline ushort f2b(float f) {
    __bf16 h = (__bf16)f;
    return __builtin_bit_cast(ushort, h);
}

// ---------------- f32 -> bf16 flat convert ----------------
__global__ void k_conv(const float* __restrict__ in, ushort* __restrict__ out, int n) {
    int i = (blockIdx.x * 256 + threadIdx.x) * 4;
    if (i < n) {
        float4 v = *(const float4*)(in + i);
        ushort4 o;
        o.x = f2b(v.x); o.y = f2b(v.y); o.z = f2b(v.z); o.w = f2b(v.w);
        *(ushort4*)(out + i) = o;
    }
}

// ---- transpose + convert: out[n][r] = bf16(in[r][n] * (n < scale_cols ? scale : 1)) ----
__global__ void k_transpose(const float* __restrict__ in, ushort* __restrict__ out,
                            int R, int Ncol, float scale, int scale_cols) {
    __shared__ float tile[32][33];
    int tx = threadIdx.x & 31, ty = threadIdx.x >> 5;   // 32 x 8
    int c0 = blockIdx.x * 32, r0 = blockIdx.y * 32;
    for (int i = 0; i < 32; i += 8)
        tile[ty + i][tx] = in[(size_t)(r0 + ty + i) * Ncol + c0 + tx];
    __syncthreads();
    for (int i = 0; i < 32; i += 8) {
        int n = c0 + ty + i;
        float v = tile[tx][ty + i];
        if (n < scale_cols) v *= scale;
        out[(size_t)n * R + r0 + tx] = f2b(v);
    }
}

// ---------------- generic m97-style GEMM (proj): C[M,N] = A * Bt^T + bias, f32 out ----------------
__global__ __launch_bounds__(256, 2) void k_gemm_bt(
    const ushort* __restrict__ A, const ushort* __restrict__ Bt,
    const float* __restrict__ bias, float* __restrict__ outv,
    int M, int N, int K)
{
    __shared__ __align__(16) ushort As[128 * 32];
    __shared__ __align__(16) ushort Bs[128 * 32];
    int tid = threadIdx.x;
    int m0 = blockIdx.y * 128, n0 = blockIdx.x * 128;
    int lane = tid & 63;
    int wm = (tid >> 7) * 64;
    int wn = ((tid >> 6) & 1) * 64;
    int lr = lane & 15, quad = lane >> 4, lk = quad * 8;

    floatx4 acc[4][4] = {};
    const ushort* ag = A  + (size_t)(m0 + (tid >> 2)) * K + (tid & 3) * 8;
    const ushort* bg = Bt + (size_t)(n0 + (tid >> 2)) * K + (tid & 3) * 8;
    ushort* asd = &As[tid * 8];
    ushort* bsd = &Bs[tid * 8];

    for (int kt = 0; kt < K; kt += 32) {
        __builtin_amdgcn_global_load_lds((const AS1 unsigned int*)(ag + kt),                  (AS3 unsigned int*)(asd),        16, 0, 0);
        __builtin_amdgcn_global_load_lds((const AS1 unsigned int*)(ag + kt + (size_t)64 * K), (AS3 unsigned int*)(asd + 2048), 16, 0, 0);
        __builtin_amdgcn_global_load_lds((const AS1 unsigned int*)(bg + kt),                  (AS3 unsigned int*)(bsd),        16, 0, 0);
        __builtin_amdgcn_global_load_lds((const AS1 unsigned int*)(bg + kt + (size_t)64 * K), (AS3 unsigned int*)(bsd + 2048), 16, 0, 0);
        asm volatile("s_waitcnt vmcnt(0)" ::: "memory");
        __syncthreads();
        bf16x8 af[4], bf[4];
        #pragma unroll
        for (int i = 0; i < 4; ++i) af[i] = *(const bf16x8*)&As[(wm + 16 * i + lr) * 32 + lk];
        #pragma unroll
        for (int j = 0; j < 4; ++j) bf[j] = *(const bf16x8*)&Bs[(wn + 16 * j + lr) * 32 + lk];
        #pragma unroll
        for (int i = 0; i < 4; ++i)
            #pragma unroll
            for (int j = 0; j < 4; ++j)
                acc[i][j] = __builtin_amdgcn_mfma_f32_16x16x32_bf16(af[i], bf[j], acc[i][j], 0, 0, 0);
        __syncthreads();
    }

    #pragma unroll
    for (int j = 0; j < 4; ++j) {
        int col = n0 + wn + 16 * j + lr;
        float bv = bias[col];
        #pragma unroll
        for (int i = 0; i < 4; ++i) {
            int row = m0 + wm + 16 * i + quad * 4;
            #pragma unroll
            for (int r = 0; r < 4; ++r)
                outv[(size_t)(row + r) * N + col] = acc[i][j][r] + bv;
        }
    }
}

// ---------------- QKV GEMM: M=8192, N=3072, K=1024 ----------------
// Q/K columns (0..2047) -> qkv[row][col], row stride 2048 (Q pre-scaled by SCQ via weights).
// V columns (2048..3071) -> vt[((b*16+h)*64+d)*2048 + t]  (pre-transposed for attention).
__global__ __launch_bounds__(256, 2) void k_gemm_qkv(
    const ushort* __restrict__ A, const ushort* __restrict__ Bt,
    const float* __restrict__ bias, ushort* __restrict__ qkv, ushort* __restrict__ vt)
{
    constexpr int K = 1024;
    __shared__ __align__(16) ushort As[128 * 32];
    __shared__ __align__(16) ushort Bs[128 * 32];
    int tid = threadIdx.x;
    int m0 = blockIdx.y * 128, n0 = blockIdx.x * 128;
    int lane = tid & 63;
    int wm = (tid >> 7) * 64;
    int wn = ((tid >> 6) & 1) * 64;
    int lr = lane & 15, quad = lane >> 4, lk = quad * 8;

    floatx4 acc[4][4] = {};
    const ushort* ag = A  + (size_t)(m0 + (tid >> 2)) * K + (tid & 3) * 8;
    const ushort* bg = Bt + (size_t)(n0 + (tid >> 2)) * K + (tid & 3) * 8;
    ushort* asd = &As[tid * 8];
    ushort* bsd = &Bs[tid * 8];

    for (int kt = 0; kt < K; kt += 32) {
        __builtin_amdgcn_global_load_lds((const AS1 unsigned int*)(ag + kt),                  (AS3 unsigned int*)(asd),        16, 0, 0);
        __builtin_amdgcn_global_load_lds((const AS1 unsigned int*)(ag + kt + (size_t)64 * K), (AS3 unsigned int*)(asd + 2048), 16, 0, 0);
        __builtin_amdgcn_global_load_lds((const AS1 unsigned int*)(bg + kt),                  (AS3 unsigned int*)(bsd),        16, 0, 0);
        __builtin_amdgcn_global_load_lds((const AS1 unsigned int*)(bg + kt + (size_t)64 * K), (AS3 unsigned int*)(bsd + 2048), 16, 0, 0);
        asm volatile("s_waitcnt vmcnt(0)" ::: "memory");
        __syncthreads();
        bf16x8 af[4], bf[4];
        #pragma unroll
        for (int i = 0; i < 4; ++i) af[i] = *(const bf16x8*)&As[(wm + 16 * i + lr) * 32 + lk];
        #pragma unroll
        for (int j = 0; j < 4; ++j) bf[j] = *(const bf16x8*)&Bs[(wn + 16 * j + lr) * 32 + lk];
        #pragma unroll
        for (int i = 0; i < 4; ++i)
            #pragma unroll
            for (int j = 0; j < 4; ++j)
                acc[i][j] = __builtin_amdgcn_mfma_f32_16x16x32_bf16(af[i], bf[j], acc[i][j], 0, 0, 0);
        __syncthreads();
    }

    int bb = m0 >> 11;   // batch index (blocks are 128-row, T=2048-aligned)
    #pragma unroll
    for (int j = 0; j < 4; ++j) {
        int col = n0 + wn + 16 * j + lr;
        float bv = bias[col];
        if (col < 1024) bv *= SCQ;
        if (col < 2048) {
            #pragma unroll
            for (int i = 0; i < 4; ++i) {
                int row = m0 + wm + 16 * i + quad * 4;
                #pragma unroll
                for (int r = 0; r < 4; ++r)
                    qkv[(size_t)(row + r) * 2048 + col] = f2b(acc[i][j][r] + bv);
            }
        } else {
            int h = (col - 2048) >> 6, d = (col - 2048) & 63;
            ushort* vbase = vt + ((size_t)(bb * 16 + h) * 64 + d) * 2048;
            #pragma unroll
            for (int i = 0; i < 4; ++i) {
                int t0 = (m0 + wm + 16 * i + quad * 4) & 2047;
                ushort4 pk;
                ((ushort*)&pk)[0] = f2b(acc[i][j][0] + bv);
                ((ushort*)&pk)[1] = f2b(acc[i][j][1] + bv);
                ((ushort*)&pk)[2] = f2b(acc[i][j][2] + bv);
                ((ushort*)&pk)[3] = f2b(acc[i][j][3] + bv);
                *(ushort4*)&vbase[t0] = pk;
            }
        }
    }
}

// ---------------- causal flash attention, round 6 ----------------
// S^T = K*Q^T; its C-layout IS the A-frag of v_mfma_f32_16x16x16_bf16, so P stays in
// registers: exp2 -> cvt_pk_bf16 -> PV MFMA (K=16). No P LDS roundtrip, no lgkm drain.
// 256-thr blocks (4 waves x 16 q-rows = 64-row q-tile), grid (16,64), pairing {i,31-i}
// over 32 q-tiles -> uniform 33 key-tile iters. Double-buffered K/V staging.
// LDS 32 KB -> 4 blocks/CU (16 waves/CU, 4 independent barrier groups).
__global__ __launch_bounds__(256, 4) void k_attn(const ushort* __restrict__ qkv,
                                                 const ushort* __restrict__ vt,
                                                 ushort* __restrict__ out)
{
    constexpr int T = 2048, SQK = 2048, C = 1024;
    __shared__ __align__(16) ushort Ks[2 * 64 * 64];   // dbuf [key][swizzled d-chunk]
    __shared__ __align__(16) ushort Vs[2 * 64 * 64];   // dbuf [dim][swizzled key-chunk]
#if !HAVE_MFMA16
    __shared__ __align__(16) ushort Ps[4 * 16 * 72];   // fallback P roundtrip
#endif
    int tid = threadIdx.x;
    int lane = tid & 63, wave = tid >> 6;
    int lr = lane & 15, quad = lane >> 4, lk = quad * 8;
    int bh = blockIdx.y;
    int b = bh >> 4, h = bh & 15;
    size_t base = (size_t)b * T * SQK;
    const ushort* kg0 = qkv + base + 1024 + h * 64;
    const ushort* vg0 = vt + (size_t)bh * 64 * 2048;

    // staging: 2 slots of 16B per thread; slot s: row = s>>3, phys chunk = s&7,
    // source chunk g = (s&7) ^ (row&7)   (row = key for K, dim for V)
    const ushort* kgs[2]; const ushort* vgs[2]; int sdst[2];
    #pragma unroll
    for (int it = 0; it < 2; ++it) {
        int s = tid + 256 * it;
        int row = s >> 3, g = (s & 7) ^ (row & 7);
        kgs[it] = kg0 + (size_t)row * SQK + g * 8;
        vgs[it] = vg0 + (size_t)row * 2048 + g * 8;
        sdst[it] = s * 8;
    }

    int c0 = (quad ^ (lr & 7)) * 8;          // K frag: physical chunk for dims 0..31
    int c1 = ((4 + quad) ^ (lr & 7)) * 8;    // K frag: physical chunk for dims 32..63
    short4v ones4 = { 0x3F80, 0x3F80, 0x3F80, 0x3F80 };   // bf16 1.0 x4

    int qts[2] = { (int)blockIdx.x, 31 - (int)blockIdx.x };
    for (int ti = 0; ti < 2; ++ti) {
        int qt = qts[ti];
        int qrow = qt * 64 + wave * 16;
        const ushort* qp = qkv + base + (size_t)(qrow + lr) * SQK + h * 64;
        bf16x8 aq0 = *(const bf16x8*)(qp + lk);
        bf16x8 aq1 = *(const bf16x8*)(qp + 32 + lk);
        floatx4 o[4] = {};
        floatx4 lacc = {};

        __syncthreads();   // all waves done with buffers from previous q-tile
        #pragma unroll
        for (int it = 0; it < 2; ++it) {
            __builtin_amdgcn_global_load_lds((const AS1 unsigned int*)(kgs[it]),
                                             (AS3 unsigned int*)&Ks[sdst[it]], 16, 0, 0);
            __builtin_amdgcn_global_load_lds((const AS1 unsigned int*)(vgs[it]),
                                             (AS3 unsigned int*)&Vs[sdst[it]], 16, 0, 0);
        }

        for (int kt = 0; kt <= qt; ++kt) {
            int cur = kt & 1;
            asm volatile("s_waitcnt vmcnt(0)" ::: "memory");
            __syncthreads();
            if (kt < qt) {   // prefetch kt+1 into the other buffer
                int nb = (cur ^ 1) * 4096;
                #pragma unroll
                for (int it = 0; it < 2; ++it) {
                    __builtin_amdgcn_global_load_lds(
                        (const AS1 unsigned int*)(kgs[it] + (size_t)(kt + 1) * 64 * SQK),
                        (AS3 unsigned int*)&Ks[nb + sdst[it]], 16, 0, 0);
                    __builtin_amdgcn_global_load_lds(
                        (const AS1 unsigned int*)(vgs[it] + (kt + 1) * 64),
                        (AS3 unsigned int*)&Vs[nb + sdst[it]], 16, 0, 0);
                }
            }
            const ushort* Kb = &Ks[cur * 4096];
            const ushort* Vb = &Vs[cur * 4096];
            bool diag = (kt == qt);
            int qloc = wave * 16 + lr;

            #pragma unroll
            for (int jk = 0; jk < 4; ++jk) {
                // --- S^T slice: 16 keys x 16 q ---
                const ushort* kr = &Kb[(16 * jk + lr) * 64];
                bf16x8 ak0 = *(const bf16x8*)(kr + c0);
                bf16x8 ak1 = *(const bf16x8*)(kr + c1);
                floatx4 z = {};
                floatx4 st = __builtin_amdgcn_mfma_f32_16x16x32_bf16(ak0, aq0, z, 0, 0, 0);
                st = __builtin_amdgcn_mfma_f32_16x16x32_bf16(ak1, aq1, st, 0, 0, 0);
                int kloc = 16 * jk + quad * 4;
                float e0, e1, e2, e3;
                if (diag) {
                    e0 = (kloc + 0 > qloc) ? 0.f : exp2f(st[0]);
                    e1 = (kloc + 1 > qloc) ? 0.f : exp2f(st[1]);
                    e2 = (kloc + 2 > qloc) ? 0.f : exp2f(st[2]);
                    e3 = (kloc + 3 > qloc) ? 0.f : exp2f(st[3]);
                } else {
                    e0 = exp2f(st[0]); e1 = exp2f(st[1]);
                    e2 = exp2f(st[2]); e3 = exp2f(st[3]);
                }
#if HAVE_MFMA16
                short4v ap;
                ap[0] = (short)f2b(e0); ap[1] = (short)f2b(e1);
                ap[2] = (short)f2b(e2); ap[3] = (short)f2b(e3);
                lacc = __builtin_amdgcn_mfma_f32_16x16x16bf16_1k(ap, ones4, lacc, 0, 0, 0);
                #pragma unroll
                for (int jd = 0; jd < 4; ++jd) {
                    int p = (2 * jk + (quad >> 1)) ^ (lr & 7);
                    short4v bv = *(const short4v*)&Vb[(16 * jd + lr) * 64 + p * 8 + (quad & 1) * 4];
                    o[jd] = __builtin_amdgcn_mfma_f32_16x16x16bf16_1k(ap, bv, o[jd], 0, 0, 0);
                }
#else
                uint2 w;
                w.x = (unsigned)f2b(e0) | ((unsigned)f2b(e1) << 16);
                w.y = (unsigned)f2b(e2) | ((unsigned)f2b(e3) << 16);
                *(uint2*)&Ps[(wave * 16 + lr) * 72 + kloc] = w;
#endif
            }
#if !HAVE_MFMA16
            asm volatile("s_waitcnt lgkmcnt(0)" ::: "memory");
            {
                bf16x8 ones;
                #pragma unroll
                for (int i = 0; i < 8; ++i) ones[i] = (__bf16)1.0f;
                bf16x8 ap0 = *(const bf16x8*)&Ps[(wave * 16 + lr) * 72 + lk];
                bf16x8 ap1 = *(const bf16x8*)&Ps[(wave * 16 + lr) * 72 + 32 + lk];
                lacc = __builtin_amdgcn_mfma_f32_16x16x32_bf16(ap0, ones, lacc, 0, 0, 0);
                lacc = __builtin_amdgcn_mfma_f32_16x16x32_bf16(ap1, ones, lacc, 0, 0, 0);
                #pragma unroll
                for (int jd = 0; jd < 4; ++jd) {
                    const ushort* vr = &Vb[(16 * jd + lr) * 64];
                    bf16x8 bv0 = *(const bf16x8*)(vr + c0);
                    bf16x8 bv1 = *(const bf16x8*)(vr + c1);
                    o[jd] = __builtin_amdgcn_mfma_f32_16x16x32_bf16(ap0, bv0, o[jd], 0, 0, 0);
                    o[jd] = __builtin_amdgcn_mfma_f32_16x16x32_bf16(ap1, bv1, o[jd], 0, 0, 0);
                }
            }
#endif
        }

        #pragma unroll
        for (int r = 0; r < 4; ++r) {
            float inv = 1.0f / lacc[r];
            int row = b * T + qrow + quad * 4 + r;
            #pragma unroll
            for (int jd = 0; jd < 4; ++jd)
                out[(size_t)row * C + h * 64 + 16 * jd + lr] = f2b(o[jd][r] * inv);
        }
    }
}

extern "C" void kernel_launch(void* const* d_in, const int* in_sizes, int n_in,
                              void* d_out, int out_size, void* d_ws, size_t ws_size,
                              hipStream_t stream) {
    const float* x      = (const float*)d_in[0];
    const float* w_attn = (const float*)d_in[1];
    const float* b_attn = (const float*)d_in[2];
    const float* w_proj = (const float*)d_in[3];
    const float* b_proj = (const float*)d_in[4];
    float* out = (float*)d_out;

    constexpr int Bb = 4, T = 2048, C = 1024;
    constexpr int M = Bb * T;   // 8192

    // workspace layout (bf16 elements): ~92 MB total
    ushort* xb  = (ushort*)d_ws;                    // M*C
    ushort* waT = xb  + (size_t)M * C;              // 3C x C
    ushort* wpT = waT + (size_t)3 * C * C;          // C x C
    ushort* qkv = wpT + (size_t)C * C;              // M x 2C  (Q|K only)
    ushort* vt  = qkv + (size_t)M * 2 * C;          // 64 bh x 64 d x T (V^T)
    ushort* ao  = vt  + (size_t)64 * 64 * T;        // M x C

    k_conv<<<(M * C / 4 + 255) / 256, 256, 0, stream>>>(x, xb, M * C);
    k_transpose<<<dim3(3 * C / 32, C / 32), 256, 0, stream>>>(w_attn, waT, C, 3 * C, SCQ, C);
    k_transpose<<<dim3(C / 32, C / 32), 256, 0, stream>>>(w_proj, wpT, C, C, 1.0f, 0);
    k_gemm_qkv<<<dim3(3 * C / 128, M / 128), 256, 0, stream>>>(xb, waT, b_attn, qkv, vt);
    k_attn<<<dim3(16, Bb * 16), 256, 0, stream>>>(qkv, vt, ao);
    k_gemm_bt<<<dim3(C / 128, M / 128), 256, 0, stream>>>(ao, wpT, b_proj, out, M, C, C);
}

// Round 7
// 256.431 us; speedup vs baseline: 1.1192x; 1.1192x over previous
//
#include <hip/hip_runtime.h>

#define AS1 __attribute__((address_space(1)))
#define AS3 __attribute__((address_space(3)))

using bf16x8  = __attribute__((ext_vector_type(8))) __bf16;
using floatx4 = __attribute__((ext_vector_type(4))) float;

#define SCQ 0.18033688f   // (1/sqrt(64)) * log2(e), folded into Q weights/bias

__device__ inline ushort f2b(float f) {
    __bf16 h = (__bf16)f;
    return __builtin_bit_cast(ushort, h);
}

// ---------------- fused prep: f32->bf16 convert of x, + both weight transposes ----------------
// blocks [0, 8192): conv x (M*C = 8388608 elems, 1024/block)
// blocks [8192, 11264): w_attn transpose 1024x3072 -> 3072x1024 (Q cols scaled by SCQ)
// blocks [11264, 12288): w_proj transpose 1024x1024 -> 1024x1024
__global__ void k_prep(const float* __restrict__ x, ushort* __restrict__ xb,
                       const float* __restrict__ wa, ushort* __restrict__ waT,
                       const float* __restrict__ wp, ushort* __restrict__ wpT)
{
    __shared__ float tile[32][33];
    int blk = blockIdx.x;
    if (blk < 8192) {
        int i = (blk * 256 + threadIdx.x) * 4;
        float4 v = *(const float4*)(x + i);
        ushort4 o;
        o.x = f2b(v.x); o.y = f2b(v.y); o.z = f2b(v.z); o.w = f2b(v.w);
        *(ushort4*)(xb + i) = o;
        return;
    }
    const float* in; ushort* out; int R, Ncol, bx, by; float scale; int scale_cols;
    if (blk < 11264) {
        int idx = blk - 8192;
        in = wa; out = waT; R = 1024; Ncol = 3072;
        bx = idx % 96; by = idx / 96; scale = SCQ; scale_cols = 1024;
    } else {
        int idx = blk - 11264;
        in = wp; out = wpT; R = 1024; Ncol = 1024;
        bx = idx % 32; by = idx / 32; scale = 1.0f; scale_cols = 0;
    }
    int tx = threadIdx.x & 31, ty = threadIdx.x >> 5;   // 32 x 8
    int c0 = bx * 32, r0 = by * 32;
    for (int i = 0; i < 32; i += 8)
        tile[ty + i][tx] = in[(size_t)(r0 + ty + i) * Ncol + c0 + tx];
    __syncthreads();
    for (int i = 0; i < 32; i += 8) {
        int n = c0 + ty + i;
        float v = tile[tx][ty + i];
        if (n < scale_cols) v *= scale;
        out[(size_t)n * R + r0 + tx] = f2b(v);
    }
}

// ---------------- BK=64 GEMM (proj): C[M,N] = A * Bt^T + bias, f32 out ----------------
__global__ __launch_bounds__(256, 2) void k_gemm_bt(
    const ushort* __restrict__ A, const ushort* __restrict__ Bt,
    const float* __restrict__ bias, float* __restrict__ outv,
    int M, int N, int K)
{
    __shared__ __align__(16) ushort As[128 * 64];
    __shared__ __align__(16) ushort Bs[128 * 64];
    int tid = threadIdx.x;
    int m0 = blockIdx.y * 128, n0 = blockIdx.x * 128;
    int lane = tid & 63;
    int wm = (tid >> 7) * 64;
    int wn = ((tid >> 6) & 1) * 64;
    int lr = lane & 15, quad = lane >> 4;

    floatx4 acc[4][4] = {};
    const ushort* ags[4]; const ushort* bgs[4]; int sdst[4];
    #pragma unroll
    for (int it = 0; it < 4; ++it) {
        int slot = tid + 256 * it;
        int row = slot >> 3, ch = slot & 7;
        ags[it] = A  + (size_t)(m0 + row) * K + ch * 8;
        bgs[it] = Bt + (size_t)(n0 + row) * K + ch * 8;
        sdst[it] = slot * 8;
    }

    for (int kt = 0; kt < K; kt += 64) {
        #pragma unroll
        for (int it = 0; it < 4; ++it) {
            __builtin_amdgcn_global_load_lds((const AS1 unsigned int*)(ags[it] + kt),
                                             (AS3 unsigned int*)&As[sdst[it]], 16, 0, 0);
            __builtin_amdgcn_global_load_lds((const AS1 unsigned int*)(bgs[it] + kt),
                                             (AS3 unsigned int*)&Bs[sdst[it]], 16, 0, 0);
        }
        asm volatile("s_waitcnt vmcnt(0)" ::: "memory");
        __syncthreads();
        bf16x8 af[4][2], bf[4][2];
        #pragma unroll
        for (int i = 0; i < 4; ++i) {
            af[i][0] = *(const bf16x8*)&As[(wm + 16 * i + lr) * 64 + quad * 8];
            af[i][1] = *(const bf16x8*)&As[(wm + 16 * i + lr) * 64 + 32 + quad * 8];
        }
        #pragma unroll
        for (int j = 0; j < 4; ++j) {
            bf[j][0] = *(const bf16x8*)&Bs[(wn + 16 * j + lr) * 64 + quad * 8];
            bf[j][1] = *(const bf16x8*)&Bs[(wn + 16 * j + lr) * 64 + 32 + quad * 8];
        }
        #pragma unroll
        for (int i = 0; i < 4; ++i)
            #pragma unroll
            for (int j = 0; j < 4; ++j) {
                acc[i][j] = __builtin_amdgcn_mfma_f32_16x16x32_bf16(af[i][0], bf[j][0], acc[i][j], 0, 0, 0);
                acc[i][j] = __builtin_amdgcn_mfma_f32_16x16x32_bf16(af[i][1], bf[j][1], acc[i][j], 0, 0, 0);
            }
        __syncthreads();
    }

    #pragma unroll
    for (int j = 0; j < 4; ++j) {
        int col = n0 + wn + 16 * j + lr;
        float bv = bias[col];
        #pragma unroll
        for (int i = 0; i < 4; ++i) {
            int row = m0 + wm + 16 * i + quad * 4;
            #pragma unroll
            for (int r = 0; r < 4; ++r)
                outv[(size_t)(row + r) * N + col] = acc[i][j][r] + bv;
        }
    }
}

// ---------------- BK=64 QKV GEMM: M=8192, N=3072, K=1024 ----------------
// Q/K columns (0..2047) -> qkv[row][col], row stride 2048 (Q pre-scaled by SCQ via weights).
// V columns (2048..3071) -> vt[((b*16+h)*64+d)*2048 + t]  (pre-transposed for attention).
__global__ __launch_bounds__(256, 2) void k_gemm_qkv(
    const ushort* __restrict__ A, const ushort* __restrict__ Bt,
    const float* __restrict__ bias, ushort* __restrict__ qkv, ushort* __restrict__ vt)
{
    constexpr int K = 1024;
    __shared__ __align__(16) ushort As[128 * 64];
    __shared__ __align__(16) ushort Bs[128 * 64];
    int tid = threadIdx.x;
    int m0 = blockIdx.y * 128, n0 = blockIdx.x * 128;
    int lane = tid & 63;
    int wm = (tid >> 7) * 64;
    int wn = ((tid >> 6) & 1) * 64;
    int lr = lane & 15, quad = lane >> 4;

    floatx4 acc[4][4] = {};
    const ushort* ags[4]; const ushort* bgs[4]; int sdst[4];
    #pragma unroll
    for (int it = 0; it < 4; ++it) {
        int slot = tid + 256 * it;
        int row = slot >> 3, ch = slot & 7;
        ags[it] = A  + (size_t)(m0 + row) * K + ch * 8;
        bgs[it] = Bt + (size_t)(n0 + row) * K + ch * 8;
        sdst[it] = slot * 8;
    }

    for (int kt = 0; kt < K; kt += 64) {
        #pragma unroll
        for (int it = 0; it < 4; ++it) {
            __builtin_amdgcn_global_load_lds((const AS1 unsigned int*)(ags[it] + kt),
                                             (AS3 unsigned int*)&As[sdst[it]], 16, 0, 0);
            __builtin_amdgcn_global_load_lds((const AS1 unsigned int*)(bgs[it] + kt),
                                             (AS3 unsigned int*)&Bs[sdst[it]], 16, 0, 0);
        }
        asm volatile("s_waitcnt vmcnt(0)" ::: "memory");
        __syncthreads();
        bf16x8 af[4][2], bf[4][2];
        #pragma unroll
        for (int i = 0; i < 4; ++i) {
            af[i][0] = *(const bf16x8*)&As[(wm + 16 * i + lr) * 64 + quad * 8];
            af[i][1] = *(const bf16x8*)&As[(wm + 16 * i + lr) * 64 + 32 + quad * 8];
        }
        #pragma unroll
        for (int j = 0; j < 4; ++j) {
            bf[j][0] = *(const bf16x8*)&Bs[(wn + 16 * j + lr) * 64 + quad * 8];
            bf[j][1] = *(const bf16x8*)&Bs[(wn + 16 * j + lr) * 64 + 32 + quad * 8];
        }
        #pragma unroll
        for (int i = 0; i < 4; ++i)
            #pragma unroll
            for (int j = 0; j < 4; ++j) {
                acc[i][j] = __builtin_amdgcn_mfma_f32_16x16x32_bf16(af[i][0], bf[j][0], acc[i][j], 0, 0, 0);
                acc[i][j] = __builtin_amdgcn_mfma_f32_16x16x32_bf16(af[i][1], bf[j][1], acc[i][j], 0, 0, 0);
            }
        __syncthreads();
    }

    int bb = m0 >> 11;   // batch index (blocks are 128-row, T=2048-aligned)
    #pragma unroll
    for (int j = 0; j < 4; ++j) {
        int col = n0 + wn + 16 * j + lr;
        float bv = bias[col];
        if (col < 1024) bv *= SCQ;
        if (col < 2048) {
            #pragma unroll
            for (int i = 0; i < 4; ++i) {
                int row = m0 + wm + 16 * i + quad * 4;
                #pragma unroll
                for (int r = 0; r < 4; ++r)
                    qkv[(size_t)(row + r) * 2048 + col] = f2b(acc[i][j][r] + bv);
            }
        } else {
            int h = (col - 2048) >> 6, d = (col - 2048) & 63;
            ushort* vbase = vt + ((size_t)(bb * 16 + h) * 64 + d) * 2048;
            #pragma unroll
            for (int i = 0; i < 4; ++i) {
                int t0 = (m0 + wm + 16 * i + quad * 4) & 2047;
                ushort4 pk;
                ((ushort*)&pk)[0] = f2b(acc[i][j][0] + bv);
                ((ushort*)&pk)[1] = f2b(acc[i][j][1] + bv);
                ((ushort*)&pk)[2] = f2b(acc[i][j][2] + bv);
                ((ushort*)&pk)[3] = f2b(acc[i][j][3] + bv);
                *(ushort4*)&vbase[t0] = pk;
            }
        }
    }
}

// ---------------- causal flash attention (round-3 kernel, verified 79 us) ----------------
__global__ __launch_bounds__(512, 4) void k_attn(const ushort* __restrict__ qkv,
                                                 const ushort* __restrict__ vt,
                                                 ushort* __restrict__ out)
{
    constexpr int T = 2048, SQK = 2048, C = 1024;
    __shared__ __align__(16) ushort Ks[64 * 64];       // [key][chunk-swizzled dim]
    __shared__ __align__(16) ushort Vs[64 * 64];       // [dim][chunk-swizzled key]
    __shared__ __align__(16) ushort Ps[8 * 16 * 72];   // per-wave P, [q][key], stride 72
    int tid = threadIdx.x;
    int lane = tid & 63, wave = tid >> 6;
    int lr = lane & 15, quad = lane >> 4, lk = quad * 8;
    int bh = blockIdx.y;
    int b = bh >> 4, h = bh & 15;
    size_t base = (size_t)b * T * SQK;
    const ushort* kg0 = qkv + base + 1024 + h * 64;
    const ushort* vg0 = vt + (size_t)bh * 64 * 2048;
    ushort* psw = &Ps[wave * 16 * 72];

    int srow = tid >> 3;                     // key (for K) / dim (for V)
    int sg   = (tid & 7) ^ (srow & 7);       // XOR-swizzled source chunk
    ushort* ksdst = &Ks[tid * 8];
    ushort* vsdst = &Vs[tid * 8];
    const ushort* kgs = kg0 + (size_t)srow * SQK + sg * 8;
    const ushort* vgs = vg0 + (size_t)srow * 2048 + sg * 8;

    bf16x8 ones;
    #pragma unroll
    for (int i = 0; i < 8; ++i) ones[i] = (__bf16)1.0f;
    int c0 = (quad ^ (lr & 7)) * 8;          // physical chunk for logical k 0..31
    int c1 = ((4 + quad) ^ (lr & 7)) * 8;    // physical chunk for logical k 32..63

    int qts[2] = { (int)blockIdx.x, 15 - (int)blockIdx.x };
    for (int ti = 0; ti < 2; ++ti) {
        int qt = qts[ti];
        int qrow = qt * 128 + wave * 16;
        int kt_d = qrow >> 6;                // this wave's diagonal tile
        const ushort* qp = qkv + base + (size_t)(qrow + lr) * SQK + h * 64;
        bf16x8 aq0 = *(const bf16x8*)(qp + lk);
        bf16x8 aq1 = *(const bf16x8*)(qp + 32 + lk);
        floatx4 o[4] = {};
        floatx4 lacc = {};
        int ktmax = 2 * qt + 1;

        for (int kt = 0; kt <= ktmax; ++kt) {
            __syncthreads();
            __builtin_amdgcn_global_load_lds((const AS1 unsigned int*)(kgs + (size_t)kt * 64 * SQK),
                                             (AS3 unsigned int*)ksdst, 16, 0, 0);
            __builtin_amdgcn_global_load_lds((const AS1 unsigned int*)(vgs + kt * 64),
                                             (AS3 unsigned int*)vsdst, 16, 0, 0);
            asm volatile("s_waitcnt vmcnt(0)" ::: "memory");
            __syncthreads();
            if (kt > kt_d) continue;

            // --- S = Q K^T ---
            floatx4 s[4];
            #pragma unroll
            for (int j = 0; j < 4; ++j) {
                const ushort* kr = &Ks[(16 * j + lr) * 64];
                bf16x8 bk0 = *(const bf16x8*)(kr + c0);
                bf16x8 bk1 = *(const bf16x8*)(kr + c1);
                floatx4 z = {};
                s[j] = __builtin_amdgcn_mfma_f32_16x16x32_bf16(aq0, bk0, z, 0, 0, 0);
                s[j] = __builtin_amdgcn_mfma_f32_16x16x32_bf16(aq1, bk1, s[j], 0, 0, 0);
            }
            // --- exp2 + pack P (mask only at the diagonal tile) ---
            if (kt == kt_d) {
                int qg = qrow + quad * 4, kb = kt * 64;
                #pragma unroll
                for (int r = 0; r < 4; ++r)
                    #pragma unroll
                    for (int j = 0; j < 4; ++j) {
                        float p = ((kb + 16 * j + lr) > (qg + r)) ? 0.f : exp2f(s[j][r]);
                        psw[(quad * 4 + r) * 72 + 16 * j + lr] = f2b(p);
                    }
            } else {
                #pragma unroll
                for (int r = 0; r < 4; ++r)
                    #pragma unroll
                    for (int j = 0; j < 4; ++j)
                        psw[(quad * 4 + r) * 72 + 16 * j + lr] = f2b(exp2f(s[j][r]));
            }
            asm volatile("s_waitcnt lgkmcnt(0)" ::: "memory");
            bf16x8 ap0 = *(const bf16x8*)&psw[lr * 72 + lk];
            bf16x8 ap1 = *(const bf16x8*)&psw[lr * 72 + 32 + lk];
            // row sums on the matrix pipe
            lacc = __builtin_amdgcn_mfma_f32_16x16x32_bf16(ap0, ones, lacc, 0, 0, 0);
            lacc = __builtin_amdgcn_mfma_f32_16x16x32_bf16(ap1, ones, lacc, 0, 0, 0);
            // --- O += P V ---
            #pragma unroll
            for (int jd = 0; jd < 4; ++jd) {
                const ushort* vr = &Vs[(16 * jd + lr) * 64];
                bf16x8 bv0 = *(const bf16x8*)(vr + c0);
                bf16x8 bv1 = *(const bf16x8*)(vr + c1);
                o[jd] = __builtin_amdgcn_mfma_f32_16x16x32_bf16(ap0, bv0, o[jd], 0, 0, 0);
                o[jd] = __builtin_amdgcn_mfma_f32_16x16x32_bf16(ap1, bv1, o[jd], 0, 0, 0);
            }
        }

        #pragma unroll
        for (int r = 0; r < 4; ++r) {
            float inv = 1.0f / lacc[r];
            int row = b * T + qrow + quad * 4 + r;
            #pragma unroll
            for (int jd = 0; jd < 4; ++jd)
                out[(size_t)row * C + h * 64 + 16 * jd + lr] = f2b(o[jd][r] * inv);
        }
    }
}

extern "C" void kernel_launch(void* const* d_in, const int* in_sizes, int n_in,
                              void* d_out, int out_size, void* d_ws, size_t ws_size,
                              hipStream_t stream) {
    const float* x      = (const float*)d_in[0];
    const float* w_attn = (const float*)d_in[1];
    const float* b_attn = (const float*)d_in[2];
    const float* w_proj = (const float*)d_in[3];
    const float* b_proj = (const float*)d_in[4];
    float* out = (float*)d_out;

    constexpr int Bb = 4, T = 2048, C = 1024;
    constexpr int M = Bb * T;   // 8192

    // workspace layout (bf16 elements): ~92 MB total
    ushort* xb  = (ushort*)d_ws;                    // M*C
    ushort* waT = xb  + (size_t)M * C;              // 3C x C
    ushort* wpT = waT + (size_t)3 * C * C;          // C x C
    ushort* qkv = wpT + (size_t)C * C;              // M x 2C  (Q|K only)
    ushort* vt  = qkv + (size_t)M * 2 * C;          // 64 bh x 64 d x T (V^T)
    ushort* ao  = vt  + (size_t)64 * 64 * T;        // M x C

    k_prep<<<12288, 256, 0, stream>>>(x, xb, w_attn, waT, w_proj, wpT);
    k_gemm_qkv<<<dim3(3 * C / 128, M / 128), 256, 0, stream>>>(xb, waT, b_attn, qkv, vt);
    k_attn<<<dim3(8, Bb * 16), 512, 0, stream>>>(qkv, vt, ao);
    k_gemm_bt<<<dim3(C / 128, M / 128), 256, 0, stream>>>(ao, wpT, b_proj, out, M, C, C);
}